// Round 5
// baseline (41.585 us; speedup 1.0000x reference)
//
#include <hip/hip_runtime.h>
#include <hip/hip_fp16.h>

#define NPART 500000
#define MPART 450000
#define NBXC 1024
#define NBYC 1024
#define KWIN 8
#define NBLK_PART 1954          // ceil(500000/256)
#define NPARTIALS 1024

// ---------------------------------------------------------------------------
// Kernel A: velocity field, vectorized 4 cells/thread along y.
// Field stored as __half2 {vx,vy} (4 MB -> L2-resident for the gathers).
// 1024 blocks -> partials[1024].
// ---------------------------------------------------------------------------
__global__ __launch_bounds__(256) void field_kernel(const float* __restrict__ pot,
                                                    const float* __restrict__ rho,
                                                    __half2* __restrict__ v,
                                                    float* __restrict__ partials) {
    const int idx = blockIdx.x * 256 + threadIdx.x;      // 0 .. 262143
    const int i  = idx >> 8;                             // row 0..1023
    const int j4 = (idx & 255) << 2;                     // col 0,4,..,1020

    const int ip = min(i + 1, NBXC - 1);
    const int im = max(i - 1, 0);
    const float sx = (ip - im == 2) ? 0.5f : 1.0f;

    const float4 c  = *reinterpret_cast<const float4*>(pot + i  * NBYC + j4);
    const float4 cu = *reinterpret_cast<const float4*>(pot + ip * NBYC + j4);
    const float4 cd = *reinterpret_cast<const float4*>(pot + im * NBYC + j4);
    const float  cl = pot[i * NBYC + max(j4 - 1, 0)];
    const float  cr = pot[i * NBYC + min(j4 + 4, NBYC - 1)];
    const float4 r4 = *reinterpret_cast<const float4*>(rho + i * NBYC + j4);

    const float vx0 = -(cu.x - cd.x) * sx;
    const float vx1 = -(cu.y - cd.y) * sx;
    const float vx2 = -(cu.z - cd.z) * sx;
    const float vx3 = -(cu.w - cd.w) * sx;

    const float vy0 = (j4 == 0)             ? -(c.y - c.x) : -(c.y - cl) * 0.5f;
    const float vy1 = -(c.z - c.x) * 0.5f;
    const float vy2 = -(c.w - c.y) * 0.5f;
    const float vy3 = (j4 + 3 == NBYC - 1)  ? -(c.w - c.z) : -(cr - c.z) * 0.5f;

    float4 st;
    st.x = __builtin_bit_cast(float, __floats2half2_rn(vx0, vy0));
    st.y = __builtin_bit_cast(float, __floats2half2_rn(vx1, vy1));
    st.z = __builtin_bit_cast(float, __floats2half2_rn(vx2, vy2));
    st.w = __builtin_bit_cast(float, __floats2half2_rn(vx3, vy3));
    *reinterpret_cast<float4*>(v + i * NBYC + j4) = st;

    float e = r4.x * (vx0 * vx0 + vy0 * vy0)
            + r4.y * (vx1 * vx1 + vy1 * vy1)
            + r4.z * (vx2 * vx2 + vy2 * vy2)
            + r4.w * (vx3 * vx3 + vy3 * vy3);
    #pragma unroll
    for (int off = 32; off > 0; off >>= 1) e += __shfl_down(e, off, 64);
    __shared__ float smem[4];
    const int lane = threadIdx.x & 63;
    const int wid  = threadIdx.x >> 6;
    if (lane == 0) smem[wid] = e;
    __syncthreads();
    if (threadIdx.x == 0) partials[blockIdx.x] = (smem[0] + smem[1]) + (smem[2] + smem[3]);
}

// ---------------------------------------------------------------------------
// Kernel C: per-particle gradient (blocks 0..1953) + energy reduction
// (block 1954). Branchless 8x12 window: 24 control-independent float4 loads
// per particle -> one load clause, latency hidden by MLP.
// ---------------------------------------------------------------------------
__global__ __launch_bounds__(256) void particle_kernel(const float* __restrict__ pos,
                                                       const float* __restrict__ nsx,
                                                       const float* __restrict__ nsy,
                                                       const __half2* __restrict__ v,
                                                       const float* __restrict__ partials,
                                                       float* __restrict__ out) {
    __shared__ float smem[4];

    if (blockIdx.x == NBLK_PART) {      // ---- energy reduction block ----
        const int t = threadIdx.x;
        float e = (partials[t] + partials[t + 256]) + (partials[t + 512] + partials[t + 768]);
        #pragma unroll
        for (int off = 32; off > 0; off >>= 1) e += __shfl_down(e, off, 64);
        const int lane = t & 63;
        const int wid  = t >> 6;
        if (lane == 0) smem[wid] = e;
        __syncthreads();
        if (t == 0) out[0] = 0.5f * ((smem[0] + smem[1]) + (smem[2] + smem[3]));
        return;
    }

    const int i = blockIdx.x * 256 + threadIdx.x;
    if (i >= NPART) return;
    if (i >= MPART) {                   // zero pad regions [M:N), [N+M:2N)
        out[1 + i]         = 0.0f;
        out[1 + NPART + i] = 0.0f;
        return;
    }

    const float px = pos[i];
    const float py = pos[NPART + i];
    const float w  = nsx[i];
    const float h  = nsy[i];

    float gpx, gpy;
    const bool large = (w >= 1.0f) || (h >= 1.0f);
    if (!large) {
        int ix = min(max((int)floorf(px), 0), NBXC - 1);
        int iy = min(max((int)floorf(py), 0), NBYC - 1);
        const float wx = fminf(fmaxf(px - (float)ix, 0.0f), 1.0f);
        const float wy = fminf(fmaxf(py - (float)iy, 0.0f), 1.0f);
        const int ix1 = min(ix + 1, NBXC - 1);
        const int iy1 = min(iy + 1, NBYC - 1);
        const float2 f00 = __half22float2(v[ix  * NBYC + iy ]);
        const float2 f10 = __half22float2(v[ix1 * NBYC + iy ]);
        const float2 f01 = __half22float2(v[ix  * NBYC + iy1]);
        const float2 f11 = __half22float2(v[ix1 * NBYC + iy1]);
        const float w00 = (1.0f - wx) * (1.0f - wy);
        const float w10 = wx * (1.0f - wy);
        const float w01 = (1.0f - wx) * wy;
        const float w11 = wx * wy;
        gpx = w00 * f00.x + w10 * f10.x + w01 * f01.x + w11 * f11.x;
        gpy = w00 * f00.y + w10 * f10.y + w01 * f01.y + w11 * f11.y;
    } else {
        const float lx = px - 0.5f * w, rx = px + 0.5f * w;
        const float ly = py - 0.5f * h, ry = py + 0.5f * h;
        const int bminx = min(max((int)floorf(lx), 0), NBXC - 1);
        const int bmaxx = min(max((int)floorf(rx), 0), NBXC - 1);
        const int bminy = min(max((int)floorf(ly), 0), NBYC - 1);
        const int bmaxy = min(max((int)floorf(ry), 0), NBYC - 1);
        // 16B-aligned y-window start, clamped so all 12 cells stay in-row
        // (no overread past v's end -> no NaN-garbage risk).
        const int by0 = min(bminy & ~3, NBYC - 12);

        float oy[12];
        #pragma unroll
        for (int k = 0; k < 12; ++k) {
            const int b = by0 + k;
            const float bl = (float)b;
            float ov = fminf(ry, bl + 1.0f) - fmaxf(ly, bl);
            oy[k] = (b <= bmaxy && ov > 0.0f) ? ov : 0.0f;
        }
        float ox[KWIN];
        #pragma unroll
        for (int k = 0; k < KWIN; ++k) {
            const int b = bminx + k;
            const float bl = (float)b;
            float ov = fminf(rx, bl + 1.0f) - fmaxf(lx, bl);
            ox[k] = (b <= bmaxx && ov > 0.0f) ? ov : 0.0f;
        }

        float afx = 0.0f, afy = 0.0f;
        #pragma unroll
        for (int kx = 0; kx < KWIN; ++kx) {
            const int bx = min(bminx + kx, NBXC - 1);
            const float4* rp = reinterpret_cast<const float4*>(v + bx * NBYC + by0);
            float4 q0 = rp[0], q1 = rp[1], q2 = rp[2];
            const float* qs0 = &q0.x;
            const float* qs1 = &q1.x;
            const float* qs2 = &q2.x;
            float sx = 0.0f, sy = 0.0f;
            #pragma unroll
            for (int k = 0; k < 4; ++k) {
                const float2 f = __half22float2(__builtin_bit_cast(__half2, qs0[k]));
                sx += f.x * oy[k];
                sy += f.y * oy[k];
            }
            #pragma unroll
            for (int k = 0; k < 4; ++k) {
                const float2 f = __half22float2(__builtin_bit_cast(__half2, qs1[k]));
                sx += f.x * oy[4 + k];
                sy += f.y * oy[4 + k];
            }
            #pragma unroll
            for (int k = 0; k < 4; ++k) {
                const float2 f = __half22float2(__builtin_bit_cast(__half2, qs2[k]));
                sx += f.x * oy[8 + k];
                sy += f.y * oy[8 + k];
            }
            afx += sx * ox[kx];
            afy += sy * ox[kx];
        }
        const float inv = 1.0f / fmaxf(w * h, 1e-30f);
        gpx = afx * inv;
        gpy = afy * inv;
    }
    out[1 + i]         = gpx;
    out[1 + NPART + i] = gpy;
}

extern "C" void kernel_launch(void* const* d_in, const int* in_sizes, int n_in,
                              void* d_out, int out_size, void* d_ws, size_t ws_size,
                              hipStream_t stream) {
    const float* pos = (const float*)d_in[0];
    const float* pot = (const float*)d_in[1];
    const float* rho = (const float*)d_in[2];
    const float* nsx = (const float*)d_in[3];
    const float* nsy = (const float*)d_in[4];
    float* out = (float*)d_out;

    __half2* v      = (__half2*)d_ws;                                     // 4 MB
    float* partials = (float*)((char*)d_ws + (size_t)NBXC * NBYC * sizeof(__half2));

    field_kernel<<<(NBXC * NBYC / 4) / 256, 256, 0, stream>>>(pot, rho, v, partials);
    particle_kernel<<<NBLK_PART + 1, 256, 0, stream>>>(pos, nsx, nsy, v, partials, out);
}

// Round 6
// 31.127 us; speedup vs baseline: 1.3360x; 1.3360x over previous
//
#include <hip/hip_runtime.h>
#include <hip/hip_fp16.h>

#define NPART 500000
#define MPART 450000
#define NBXC 1024
#define NBYC 1024
#define KWIN 8
#define NBLK_PART 1954          // ceil(500000/256)

// ---------------------------------------------------------------------------
// Kernel A: velocity field, vectorized 4 cells/thread along y.
// Field stored as __half2 {vx,vy} (4 MB -> L2-resident for the gathers).
// 1024 blocks -> partials[1024].
// ---------------------------------------------------------------------------
__global__ __launch_bounds__(256) void field_kernel(const float* __restrict__ pot,
                                                    const float* __restrict__ rho,
                                                    __half2* __restrict__ v,
                                                    float* __restrict__ partials) {
    const int idx = blockIdx.x * 256 + threadIdx.x;      // 0 .. 262143
    const int i  = idx >> 8;                             // row 0..1023
    const int j4 = (idx & 255) << 2;                     // col 0,4,..,1020

    const int ip = min(i + 1, NBXC - 1);
    const int im = max(i - 1, 0);
    const float sx = (ip - im == 2) ? 0.5f : 1.0f;

    const float4 c  = *reinterpret_cast<const float4*>(pot + i  * NBYC + j4);
    const float4 cu = *reinterpret_cast<const float4*>(pot + ip * NBYC + j4);
    const float4 cd = *reinterpret_cast<const float4*>(pot + im * NBYC + j4);
    const float  cl = pot[i * NBYC + max(j4 - 1, 0)];
    const float  cr = pot[i * NBYC + min(j4 + 4, NBYC - 1)];
    const float4 r4 = *reinterpret_cast<const float4*>(rho + i * NBYC + j4);

    const float vx0 = -(cu.x - cd.x) * sx;
    const float vx1 = -(cu.y - cd.y) * sx;
    const float vx2 = -(cu.z - cd.z) * sx;
    const float vx3 = -(cu.w - cd.w) * sx;

    const float vy0 = (j4 == 0)             ? -(c.y - c.x) : -(c.y - cl) * 0.5f;
    const float vy1 = -(c.z - c.x) * 0.5f;
    const float vy2 = -(c.w - c.y) * 0.5f;
    const float vy3 = (j4 + 3 == NBYC - 1)  ? -(c.w - c.z) : -(cr - c.z) * 0.5f;

    float4 st;
    st.x = __builtin_bit_cast(float, __floats2half2_rn(vx0, vy0));
    st.y = __builtin_bit_cast(float, __floats2half2_rn(vx1, vy1));
    st.z = __builtin_bit_cast(float, __floats2half2_rn(vx2, vy2));
    st.w = __builtin_bit_cast(float, __floats2half2_rn(vx3, vy3));
    *reinterpret_cast<float4*>(v + i * NBYC + j4) = st;

    float e = r4.x * (vx0 * vx0 + vy0 * vy0)
            + r4.y * (vx1 * vx1 + vy1 * vy1)
            + r4.z * (vx2 * vx2 + vy2 * vy2)
            + r4.w * (vx3 * vx3 + vy3 * vy3);
    #pragma unroll
    for (int off = 32; off > 0; off >>= 1) e += __shfl_down(e, off, 64);
    __shared__ float smem[4];
    const int lane = threadIdx.x & 63;
    const int wid  = threadIdx.x >> 6;
    if (lane == 0) smem[wid] = e;
    __syncthreads();
    if (threadIdx.x == 0) partials[blockIdx.x] = (smem[0] + smem[1]) + (smem[2] + smem[3]);
}

// ---------------------------------------------------------------------------
// Kernel C: per-particle gradient (blocks 0..1953) + energy reduction
// (block 1954). Branchy kx-loop: exec-masked lanes skip their row loads,
// keeping L2 gather traffic at ~4 active rows/particle (round-5 lesson:
// branchless doubles L2 bytes and costs ~8us).
// ---------------------------------------------------------------------------
__global__ __launch_bounds__(256) void particle_kernel(const float* __restrict__ pos,
                                                       const float* __restrict__ nsx,
                                                       const float* __restrict__ nsy,
                                                       const __half2* __restrict__ v,
                                                       const float* __restrict__ partials,
                                                       float* __restrict__ out) {
    __shared__ float smem[4];

    if (blockIdx.x == NBLK_PART) {      // ---- energy reduction block ----
        const int t = threadIdx.x;
        float e = (partials[t] + partials[t + 256]) + (partials[t + 512] + partials[t + 768]);
        #pragma unroll
        for (int off = 32; off > 0; off >>= 1) e += __shfl_down(e, off, 64);
        const int lane = t & 63;
        const int wid  = t >> 6;
        if (lane == 0) smem[wid] = e;
        __syncthreads();
        if (t == 0) out[0] = 0.5f * ((smem[0] + smem[1]) + (smem[2] + smem[3]));
        return;
    }

    const int i = blockIdx.x * 256 + threadIdx.x;
    if (i >= NPART) return;
    if (i >= MPART) {                   // zero pad regions [M:N), [N+M:2N)
        out[1 + i]         = 0.0f;
        out[1 + NPART + i] = 0.0f;
        return;
    }

    const float px = pos[i];
    const float py = pos[NPART + i];
    const float w  = nsx[i];
    const float h  = nsy[i];

    float gpx, gpy;
    const bool large = (w >= 1.0f) || (h >= 1.0f);
    if (!large) {
        int ix = min(max((int)floorf(px), 0), NBXC - 1);
        int iy = min(max((int)floorf(py), 0), NBYC - 1);
        const float wx = fminf(fmaxf(px - (float)ix, 0.0f), 1.0f);
        const float wy = fminf(fmaxf(py - (float)iy, 0.0f), 1.0f);
        const int ix1 = min(ix + 1, NBXC - 1);
        const int iy1 = min(iy + 1, NBYC - 1);
        const float2 f00 = __half22float2(v[ix  * NBYC + iy ]);
        const float2 f10 = __half22float2(v[ix1 * NBYC + iy ]);
        const float2 f01 = __half22float2(v[ix  * NBYC + iy1]);
        const float2 f11 = __half22float2(v[ix1 * NBYC + iy1]);
        const float w00 = (1.0f - wx) * (1.0f - wy);
        const float w10 = wx * (1.0f - wy);
        const float w01 = (1.0f - wx) * wy;
        const float w11 = wx * wy;
        gpx = w00 * f00.x + w10 * f10.x + w01 * f01.x + w11 * f11.x;
        gpy = w00 * f00.y + w10 * f10.y + w01 * f01.y + w11 * f11.y;
    } else {
        const float lx = px - 0.5f * w, rx = px + 0.5f * w;
        const float ly = py - 0.5f * h, ry = py + 0.5f * h;
        const int bminx = min(max((int)floorf(lx), 0), NBXC - 1);
        const int bmaxx = min(max((int)floorf(rx), 0), NBXC - 1);
        const int bminy = min(max((int)floorf(ly), 0), NBYC - 1);
        const int bmaxy = min(max((int)floorf(ry), 0), NBYC - 1);
        // 16B-aligned y-window start, clamped so all 12 cells stay in-row
        // (no overread past v's end -> no NaN-garbage risk).
        const int by0 = min(bminy & ~3, NBYC - 12);

        float oy[12];
        #pragma unroll
        for (int k = 0; k < 12; ++k) {
            const int b = by0 + k;
            const float bl = (float)b;
            float ov = fminf(ry, bl + 1.0f) - fmaxf(ly, bl);
            oy[k] = (b <= bmaxy && ov > 0.0f) ? ov : 0.0f;
        }

        float afx = 0.0f, afy = 0.0f;
        #pragma unroll
        for (int kx = 0; kx < KWIN; ++kx) {
            const int b = bminx + kx;
            const float bl = (float)b;
            float ov = fminf(rx, bl + 1.0f) - fmaxf(lx, bl);
            ov = (b <= bmaxx && ov > 0.0f) ? ov : 0.0f;
            if (ov == 0.0f) continue;          // exec-masked lanes skip loads
            const int bx = min(b, NBXC - 1);
            const float4* rp = reinterpret_cast<const float4*>(v + bx * NBYC + by0);
            float4 q0 = rp[0], q1 = rp[1], q2 = rp[2];
            const float* qs0 = &q0.x;
            const float* qs1 = &q1.x;
            const float* qs2 = &q2.x;
            float sx = 0.0f, sy = 0.0f;
            #pragma unroll
            for (int k = 0; k < 4; ++k) {
                const float2 f = __half22float2(__builtin_bit_cast(__half2, qs0[k]));
                sx += f.x * oy[k];
                sy += f.y * oy[k];
            }
            #pragma unroll
            for (int k = 0; k < 4; ++k) {
                const float2 f = __half22float2(__builtin_bit_cast(__half2, qs1[k]));
                sx += f.x * oy[4 + k];
                sy += f.y * oy[4 + k];
            }
            #pragma unroll
            for (int k = 0; k < 4; ++k) {
                const float2 f = __half22float2(__builtin_bit_cast(__half2, qs2[k]));
                sx += f.x * oy[8 + k];
                sy += f.y * oy[8 + k];
            }
            afx += sx * ov;
            afy += sy * ov;
        }
        const float inv = 1.0f / fmaxf(w * h, 1e-30f);
        gpx = afx * inv;
        gpy = afy * inv;
    }
    out[1 + i]         = gpx;
    out[1 + NPART + i] = gpy;
}

extern "C" void kernel_launch(void* const* d_in, const int* in_sizes, int n_in,
                              void* d_out, int out_size, void* d_ws, size_t ws_size,
                              hipStream_t stream) {
    const float* pos = (const float*)d_in[0];
    const float* pot = (const float*)d_in[1];
    const float* rho = (const float*)d_in[2];
    const float* nsx = (const float*)d_in[3];
    const float* nsy = (const float*)d_in[4];
    float* out = (float*)d_out;

    __half2* v      = (__half2*)d_ws;                                     // 4 MB
    float* partials = (float*)((char*)d_ws + (size_t)NBXC * NBYC * sizeof(__half2));

    field_kernel<<<(NBXC * NBYC / 4) / 256, 256, 0, stream>>>(pot, rho, v, partials);
    particle_kernel<<<NBLK_PART + 1, 256, 0, stream>>>(pos, nsx, nsy, v, partials, out);
}